// Round 11
// baseline (192.372 us; speedup 1.0000x reference)
//
#include <hip/hip_runtime.h>
#include <hip/hip_bf16.h>

typedef __bf16 bf16;
typedef __bf16 bf16x8 __attribute__((ext_vector_type(8)));
typedef float floatx4 __attribute__((ext_vector_type(4)));

// B=2, T=512, C=8, D=512, H=8, dk=64. M = B*T*C = 8192.
// ws regions (R = 8192*512 bf16 = 8.39 MB): r0 r1 r2 r3 | WT (2 MB) = 35.6 MB
// Chain: wtr -> WT ; gemm_qkv (r9-proven 128x256, 45us) -> r0,r1,r2 ;
// mask_cvt (int32 -> additive bf16, into DEAD WT[0..1] panels) ;
// attn QBLK=64 swapped-QK, bf16 mask (r0,r1,r2)->r3 ;
// gemm_o (r10-proven 64x128 high-TLP) -> d_out.
//
// r10 lesson: full-N qkv re-reads B 128x (192MB) -> worse than r9's 222MB
// mix. r9's 128x256 = measured optimum (tile-space bracketed both sides).
// r9/r10 totals equal despite qkv +11us -> r10's gemm_o is ~11us faster;
// this round composes best-measured parts + halves attn's mask stream.

#define AS1 __attribute__((address_space(1)))
#define AS3 __attribute__((address_space(3)))

__device__ __forceinline__ void gload_lds16(const bf16* g, bf16* l) {
    __builtin_amdgcn_global_load_lds((const AS1 unsigned int*)g,
                                     (AS3 unsigned int*)l, 16, 0, 0);
}

union Pack8 { bf16 h[8]; uint4 u; };
union Pack4 { bf16 h[4]; unsigned long long u; };

__device__ __forceinline__ void store_pack8(bf16* dst, float4 a, float4 b) {
    Pack8 p;
    p.h[0] = (bf16)a.x; p.h[1] = (bf16)a.y; p.h[2] = (bf16)a.z; p.h[3] = (bf16)a.w;
    p.h[4] = (bf16)b.x; p.h[5] = (bf16)b.y; p.h[6] = (bf16)b.z; p.h[7] = (bf16)b.w;
    *(uint4*)dst = p.u;
}

// ---------------- weight transpose W[K][N] fp32 -> WT[N][K] bf16 -------------
__global__ __launch_bounds__(256) void wtr_kernel(
    const float* __restrict__ Wq, const float* __restrict__ Wk,
    const float* __restrict__ Wv, const float* __restrict__ Wo,
    bf16* __restrict__ WT)
{
    __shared__ float Ts[64][65];
    const int tid = threadIdx.x;
    const int k0 = blockIdx.x * 64;
    const int n0 = blockIdx.y * 64;
    const int z  = blockIdx.z;
    const float* W = (z == 0) ? Wq : (z == 1) ? Wk : (z == 2) ? Wv : Wo;
    bf16* O = WT + (size_t)z * 512 * 512;
    #pragma unroll
    for (int i = 0; i < 16; i++) {
        const int r = i * 4 + (tid >> 6), c = tid & 63;
        Ts[r][c] = W[(size_t)(k0 + r) * 512 + n0 + c];
    }
    __syncthreads();
    #pragma unroll
    for (int i = 0; i < 16; i++) {
        const int a = i * 4 + (tid >> 6), c = tid & 63;
        O[(size_t)(n0 + a) * 512 + k0 + c] = (bf16)Ts[c][a];
    }
}

// ---------------- mask int32 -> additive bf16 (0 / -1e9) ---------------------
// Runs AFTER gemm_qkv (stream order); writes into the dead WT[0..1] panels.
__global__ __launch_bounds__(256) void mask_cvt(
    const int* __restrict__ m, bf16* __restrict__ o)
{
    const size_t i = ((size_t)blockIdx.x * 256 + threadIdx.x) * 8;
    const int4 a = *(const int4*)(m + i);
    const int4 b = *(const int4*)(m + i + 4);
    Pack8 p;
    p.h[0] = (a.x == 0) ? (bf16)(-1.0e9f) : (bf16)0.0f;
    p.h[1] = (a.y == 0) ? (bf16)(-1.0e9f) : (bf16)0.0f;
    p.h[2] = (a.z == 0) ? (bf16)(-1.0e9f) : (bf16)0.0f;
    p.h[3] = (a.w == 0) ? (bf16)(-1.0e9f) : (bf16)0.0f;
    p.h[4] = (b.x == 0) ? (bf16)(-1.0e9f) : (bf16)0.0f;
    p.h[5] = (b.y == 0) ? (bf16)(-1.0e9f) : (bf16)0.0f;
    p.h[6] = (b.z == 0) ? (bf16)(-1.0e9f) : (bf16)0.0f;
    p.h[7] = (b.w == 0) ? (bf16)(-1.0e9f) : (bf16)0.0f;
    *(uint4*)(o + i) = p.u;
}

// ---------------- merged Q/K/V projection GEMM: 128x256 tile (r9 exact) ------
// Grid (64,2,3), 512 thr = 8 waves (2x4), wave = 64x64 (acc[4][4] in AGPR).
// A fp32 reg-staged+cvt (read 2x total); B bf16 via global_load_lds.
// Single-buffer, 2x __syncthreads per iter. Measured 45us.
__global__ __launch_bounds__(512, 3) void gemm_qkv(
    const float* __restrict__ Aq, const float* __restrict__ Ak,
    const float* __restrict__ Av, const bf16* __restrict__ WT,
    const float* __restrict__ Bq, const float* __restrict__ Bk,
    const float* __restrict__ Bv,
    bf16* __restrict__ Oq, bf16* __restrict__ Ok, bf16* __restrict__ Ov)
{
    __shared__ __align__(16) bf16 smem[17408];   // 34816 B (Tsm overlay size)
    bf16* Asm = smem;            // 128x32 = 4096 elems (8 KB)
    bf16* Bsm = smem + 4096;     // 256x32 = 8192 elems (16 KB)

    const int z = blockIdx.z;
    const float* A    = (z == 0) ? Aq : (z == 1) ? Ak : Av;
    const float* bias = (z == 0) ? Bq : (z == 1) ? Bk : Bv;
    bf16* out         = (z == 0) ? Oq : (z == 1) ? Ok : Ov;
    const bf16* BT = WT + (size_t)z * 262144;
    const float scale = (z == 0) ? 0.125f : 1.0f;

    const int tid  = threadIdx.x;
    const int lane = tid & 63;
    const int wave = tid >> 6;
    const int quad = lane >> 4;
    const int l16  = lane & 15;
    const int mblk = blockIdx.x * 128;
    const int nblk = blockIdx.y * 256;

    const int srowA = tid >> 2;
    const int scolA = (tid & 3) * 8;
    const float* Ag = A + (size_t)(mblk + srowA) * 512 + scolA;
    const int aoff = srowA * 32 + scolA;
    const int srowB = wave * 16 + (lane >> 2);
    const int scolB = (lane & 3) * 8;
    const bf16* Bg0 = BT + (size_t)(nblk + srowB) * 512 + scolB;
    const bf16* Bg1 = Bg0 + (size_t)128 * 512;
    bf16* Bl0 = Bsm + wave * 16 * 32;
    bf16* Bl1 = Bsm + (128 + wave * 16) * 32;

    const int wr = (wave >> 2) * 64;     // 2 wave-rows
    const int wc = (wave & 3) * 64;      // 4 wave-cols

    floatx4 acc[4][4] = {};
    for (int k0 = 0; k0 < 512; k0 += 32) {
        gload_lds16(Bg0 + k0, Bl0);
        gload_lds16(Bg1 + k0, Bl1);
        float4 x0 = *(const float4*)(Ag + k0);
        float4 x1 = *(const float4*)(Ag + k0 + 4);
        store_pack8(Asm + aoff, x0, x1);
        __syncthreads();
        bf16x8 a[4], b[4];
        #pragma unroll
        for (int mt = 0; mt < 4; mt++)
            a[mt] = *(const bf16x8*)(Asm + (wr + mt * 16 + l16) * 32 + quad * 8);
        #pragma unroll
        for (int nt = 0; nt < 4; nt++)
            b[nt] = *(const bf16x8*)(Bsm + (wc + nt * 16 + l16) * 32 + quad * 8);
        #pragma unroll
        for (int mt = 0; mt < 4; mt++)
            #pragma unroll
            for (int nt = 0; nt < 4; nt++)
                acc[mt][nt] = __builtin_amdgcn_mfma_f32_16x16x32_bf16(
                    a[mt], b[nt], acc[mt][nt], 0, 0, 0);
        __syncthreads();
    }

    if (z != 2) {
        #pragma unroll
        for (int mt = 0; mt < 4; mt++) {
            #pragma unroll
            for (int nt = 0; nt < 4; nt++) {
                const int colg = nblk + wc + nt * 16 + l16;
                const float bb = bias[colg];
                #pragma unroll
                for (int r = 0; r < 4; r++) {
                    const int rowg = mblk + wr + mt * 16 + quad * 4 + r;
                    const float v = (acc[mt][nt][r] + bb) * scale;
                    const int b_ = rowg >> 12;
                    const int t_ = (rowg >> 3) & 511;
                    const int c  = rowg & 7;
                    const int h  = colg >> 6;
                    const int d  = colg & 63;
                    const int hd = b_ * 64 + h * 8 + c;
                    out[((size_t)hd * 512 + t_) * 64 + d] = (bf16)v;
                }
            }
        }
    } else {
        // V^T transpose epilogue: 2 col-chunks of 128 through Tsm[128][136].
        typedef bf16 TsmRow[136];
        TsmRow* Tsm = (TsmRow*)smem;
        const int b_ = mblk >> 12;
        const int t0 = (mblk >> 3) & 511;
        #pragma unroll
        for (int cb = 0; cb < 2; cb++) {
            if (((wave & 3) >> 1) == cb) {   // waves owning cols [cb*128,+128)
                #pragma unroll
                for (int mt = 0; mt < 4; mt++) {
                    #pragma unroll
                    for (int nt = 0; nt < 4; nt++) {
                        const int clg = wc + nt * 16 + l16;   // local col
                        const float bb = bias[nblk + clg];
                        const int cl = clg - cb * 128;
                        #pragma unroll
                        for (int r = 0; r < 4; r++)
                            Tsm[wr + mt * 16 + quad * 4 + r][cl] =
                                (bf16)(acc[mt][nt][r] + bb);
                    }
                }
            }
            __syncthreads();
            #pragma unroll
            for (int e = tid; e < 1024; e += 512) {
                const int col = e >> 3, c = e & 7;
                const int gcol = nblk + cb * 128 + col;
                const int h = gcol >> 6, d = gcol & 63;
                const int hd = b_ * 64 + h * 8 + c;
                Pack8 lo, hi;
                #pragma unroll
                for (int j = 0; j < 8; j++) lo.h[j] = Tsm[j * 8 + c][col];
                #pragma unroll
                for (int j = 0; j < 8; j++) hi.h[j] = Tsm[(j + 8) * 8 + c][col];
                bf16* dst = out + ((size_t)hd * 64 + d) * 512 + t0;
                *(uint4*)dst = lo.u;
                *(uint4*)(dst + 8) = hi.u;
            }
            __syncthreads();
        }
    }
}

// ---------------- output projection GEMM: 64x128, 4 waves (r10 exact) --------
__global__ __launch_bounds__(256) void gemm_o(
    const bf16* __restrict__ A, const bf16* __restrict__ BT,
    const float* __restrict__ bias, float* __restrict__ out)
{
    __shared__ bf16 Asm[64 * 32];
    __shared__ bf16 Bsm[128 * 32];
    const int tid  = threadIdx.x;
    const int lane = tid & 63;
    const int wave = tid >> 6;
    const int quad = lane >> 4;
    const int l16  = lane & 15;
    const int mblk = blockIdx.x * 64;
    const int nblk = blockIdx.y * 128;

    const int srow = wave * 16 + (lane >> 2);
    const int scol = (lane & 3) * 8;
    const bf16* Ag  = A + (size_t)(mblk + srow) * 512 + scol;
    const bf16* Bg0 = BT + (size_t)(nblk + srow) * 512 + scol;
    const bf16* Bg1 = Bg0 + (size_t)64 * 512;
    bf16* Al  = Asm + wave * 16 * 32;
    bf16* Bl0 = Bsm + wave * 16 * 32;
    bf16* Bl1 = Bsm + (64 + wave * 16) * 32;

    const int wr = (wave >> 1) * 32;
    const int wc = (wave & 1) * 64;

    floatx4 acc[2][4] = {};
    for (int k0 = 0; k0 < 512; k0 += 32) {
        gload_lds16(Ag + k0,  Al);
        gload_lds16(Bg0 + k0, Bl0);
        gload_lds16(Bg1 + k0, Bl1);
        __syncthreads();
        bf16x8 a[2], b[4];
        #pragma unroll
        for (int mt = 0; mt < 2; mt++)
            a[mt] = *(const bf16x8*)(Asm + (wr + mt * 16 + l16) * 32 + quad * 8);
        #pragma unroll
        for (int nt = 0; nt < 4; nt++)
            b[nt] = *(const bf16x8*)(Bsm + (wc + nt * 16 + l16) * 32 + quad * 8);
        #pragma unroll
        for (int mt = 0; mt < 2; mt++)
            #pragma unroll
            for (int nt = 0; nt < 4; nt++)
                acc[mt][nt] = __builtin_amdgcn_mfma_f32_16x16x32_bf16(
                    a[mt], b[nt], acc[mt][nt], 0, 0, 0);
        __syncthreads();
    }

    #pragma unroll
    for (int mt = 0; mt < 2; mt++) {
        #pragma unroll
        for (int nt = 0; nt < 4; nt++) {
            const int colg = nblk + wc + nt * 16 + l16;
            const float bb = bias[colg];
            #pragma unroll
            for (int r = 0; r < 4; r++) {
                const int rowg = mblk + wr + mt * 16 + quad * 4 + r;
                out[(size_t)rowg * 512 + colg] = acc[mt][nt][r] + bb;
            }
        }
    }
}

// ---------------- attention: QBLK=64, swapped QK^T, bf16 mask ----------------
#define PST 520

__global__ __launch_bounds__(256, 2) void attn_kernel(
    const bf16* __restrict__ Qws, const bf16* __restrict__ Kws,
    const bf16* __restrict__ Vtws, const bf16* __restrict__ maskbf,
    bf16* __restrict__ Xws)
{
    __shared__ bf16 Psm[64][PST];
    __shared__ float redM[4][64];
    __shared__ float redS[4][64];
    const int tid  = threadIdx.x;
    const int wave = tid >> 6;
    const int lane = tid & 63;
    const int quad = lane >> 4;
    const int l16  = lane & 15;
    const int s_ = blockIdx.x;
    const int o_ = ((s_ & 7) << 7) | (s_ >> 3);
    const int hd = o_ >> 3;
    const int qt = o_ & 7;
    const int q0 = qt * 64;
    const int b = hd >> 6;
    const int h = (hd >> 3) & 7;
    const int c = hd & 7;

    const bf16* Qh = Qws + (size_t)hd * 512 * 64;
    const bf16* Kh = Kws + (size_t)hd * 512 * 64;
    const bf16* mp = maskbf + ((size_t)b * 512 + q0) * 512;

    bf16x8 aq[4][2];
    #pragma unroll
    for (int s = 0; s < 4; s++) {
        aq[s][0] = *(const bf16x8*)(Qh + (size_t)(q0 + s * 16 + l16) * 64 + quad * 8);
        aq[s][1] = *(const bf16x8*)(Qh + (size_t)(q0 + s * 16 + l16) * 64 + 32 + quad * 8);
    }

    floatx4 sv[4][8];
    #pragma unroll
    for (int s = 0; s < 4; s++)
        #pragma unroll
        for (int nt = 0; nt < 8; nt++)
            sv[s][nt] = (floatx4){0.f, 0.f, 0.f, 0.f};

    #pragma unroll
    for (int nt = 0; nt < 8; nt++) {
        const int s0 = wave * 128 + nt * 16;
        bf16x8 bk0 = *(const bf16x8*)(Kh + (size_t)(s0 + l16) * 64 + quad * 8);
        bf16x8 bk1 = *(const bf16x8*)(Kh + (size_t)(s0 + l16) * 64 + 32 + quad * 8);
        #pragma unroll
        for (int s = 0; s < 4; s++) {
            sv[s][nt] = __builtin_amdgcn_mfma_f32_16x16x32_bf16(
                bk0, aq[s][0], sv[s][nt], 0, 0, 0);
            sv[s][nt] = __builtin_amdgcn_mfma_f32_16x16x32_bf16(
                bk1, aq[s][1], sv[s][nt], 0, 0, 0);
        }
    }

    float mx[4] = {-3.0e38f, -3.0e38f, -3.0e38f, -3.0e38f};
    #pragma unroll
    for (int s = 0; s < 4; s++)
        #pragma unroll
        for (int nt = 0; nt < 8; nt++) {
            Pack4 mv;
            mv.u = *(const unsigned long long*)(
                mp + (size_t)(s * 16 + l16) * 512 + wave * 128 + nt * 16 + quad * 4);
            float v0 = sv[s][nt][0] + (float)mv.h[0];
            float v1 = sv[s][nt][1] + (float)mv.h[1];
            float v2 = sv[s][nt][2] + (float)mv.h[2];
            float v3 = sv[s][nt][3] + (float)mv.h[3];
            sv[s][nt][0] = v0; sv[s][nt][1] = v1;
            sv[s][nt][2] = v2; sv[s][nt][3] = v3;
            mx[s] = fmaxf(mx[s], fmaxf(fmaxf(v0, v1), fmaxf(v2, v3)));
        }
    #pragma unroll
    for (int s = 0; s < 4; s++) {
        mx[s] = fmaxf(mx[s], __shfl_xor(mx[s], 16, 64));
        mx[s] = fmaxf(mx[s], __shfl_xor(mx[s], 32, 64));
    }
    if (quad == 0)
        #pragma unroll
        for (int s = 0; s < 4; s++) redM[wave][s * 16 + l16] = mx[s];
    __syncthreads();

    float mf[4], sum[4] = {0.f, 0.f, 0.f, 0.f};
    #pragma unroll
    for (int s = 0; s < 4; s++) {
        const int qr = s * 16 + l16;
        mf[s] = fmaxf(fmaxf(redM[0][qr], redM[1][qr]),
                      fmaxf(redM[2][qr], redM[3][qr]));
    }
    #pragma unroll
    for (int s = 0; s < 4; s++)
        #pragma unroll
        for (int nt = 0; nt < 8; nt++)
            #pragma unroll
            for (int r = 0; r < 4; r++) {
                const float e = __expf(sv[s][nt][r] - mf[s]);
                sv[s][nt][r] = e;
                sum[s] += e;
            }
    #pragma unroll
    for (int s = 0; s < 4; s++) {
        sum[s] += __shfl_xor(sum[s], 16, 64);
        sum[s] += __shfl_xor(sum[s], 32, 64);
    }
    if (quad == 0)
        #pragma unroll
        for (int s = 0; s < 4; s++) redS[wave][s * 16 + l16] = sum[s];
    __syncthreads();

    float inv[4];
    #pragma unroll
    for (int s = 0; s < 4; s++) {
        const int qr = s * 16 + l16;
        inv[s] = 1.f / (redS[0][qr] + redS[1][qr] + redS[2][qr] + redS[3][qr]);
    }
    #pragma unroll
    for (int s = 0; s < 4; s++)
        #pragma unroll
        for (int nt = 0; nt < 8; nt++) {
            Pack4 pk;
            #pragma unroll
            for (int r = 0; r < 4; r++)
                pk.h[r] = (bf16)(sv[s][nt][r] * inv[s]);
            *(unsigned long long*)&Psm[s * 16 + l16][wave * 128 + nt * 16 + quad * 4]
                = pk.u;
        }
    __syncthreads();

    const bf16* Vh = Vtws + (size_t)hd * 64 * 512;
    const int d0 = wave * 16;
    floatx4 o[4] = {};
    #pragma unroll
    for (int ks = 0; ks < 16; ks++) {
        bf16x8 bv = *(const bf16x8*)(Vh + (size_t)(d0 + l16) * 512 + ks * 32 + quad * 8);
        #pragma unroll
        for (int rt = 0; rt < 4; rt++) {
            bf16x8 ap = *(const bf16x8*)(&Psm[rt * 16 + l16][ks * 32 + quad * 8]);
            o[rt] = __builtin_amdgcn_mfma_f32_16x16x32_bf16(ap, bv, o[rt], 0, 0, 0);
        }
    }
    #pragma unroll
    for (int rt = 0; rt < 4; rt++)
        #pragma unroll
        for (int r = 0; r < 4; r++) {
            const int q = q0 + rt * 16 + quad * 4 + r;
            const size_t row = ((size_t)b * 512 + q) * 8 + c;
            Xws[row * 512 + h * 64 + d0 + l16] = (bf16)o[rt][r];
        }
}

extern "C" void kernel_launch(void* const* d_in, const int* in_sizes, int n_in,
                              void* d_out, int out_size, void* d_ws, size_t ws_size,
                              hipStream_t stream)
{
    const float* qin  = (const float*)d_in[0];
    const float* kin  = (const float*)d_in[1];
    const float* vin  = (const float*)d_in[2];
    const int*   mask = (const int*)d_in[3];
    const float* Bq = (const float*)d_in[5];
    const float* Bk = (const float*)d_in[7];
    const float* Bv = (const float*)d_in[9];
    const float* Bo = (const float*)d_in[11];
    float* out = (float*)d_out;

    const size_t R = (size_t)8192 * 512;
    bf16* r0 = (bf16*)d_ws;
    bf16* r1 = r0 + R;
    bf16* r2 = r1 + R;
    bf16* r3 = r2 + R;
    bf16* WT = r3 + R;

    wtr_kernel<<<dim3(8, 8, 4), dim3(256), 0, stream>>>(
        (const float*)d_in[4], (const float*)d_in[6],
        (const float*)d_in[8], (const float*)d_in[10], WT);
    gemm_qkv<<<dim3(64, 2, 3), dim3(512), 0, stream>>>(
        qin, kin, vin, WT, Bq, Bk, Bv, r0, r1, r2);
    // WT[0..1] (Wq^T, Wk^T) are dead after gemm_qkv: reuse for bf16 mask.
    mask_cvt<<<dim3(256), dim3(256), 0, stream>>>(mask, WT);
    attn_kernel<<<dim3(1024), dim3(256), 0, stream>>>(
        r0, r1, r2, WT, r3);
    gemm_o<<<dim3(128, 4), dim3(256), 0, stream>>>(
        r3, WT + (size_t)3 * 262144, Bo, out);
}

// Round 12
// 187.620 us; speedup vs baseline: 1.0253x; 1.0253x over previous
//
#include <hip/hip_runtime.h>
#include <hip/hip_bf16.h>

typedef __bf16 bf16;
typedef __bf16 bf16x8 __attribute__((ext_vector_type(8)));
typedef float floatx4 __attribute__((ext_vector_type(4)));

// B=2, T=512, C=8, D=512, H=8, dk=64. M = B*T*C = 8192.
// ws regions (R = 8192*512 bf16 = 8.39 MB): r0 r1 r2 r3 | WT (2 MB) = 35.6 MB
// Chain: wtr -> WT ; gemm_qkv (r9-proven 128x256, 45us) -> r0,r1,r2 ;
// attn QBLK=64 swapped-QK, int4 mask (r0,r1,r2)->r3 ;
// gemm_o (r10 64x128 high-TLP) -> d_out.
//
// r11 lesson: bf16-mask attn was +10us vs int4-mask (half the bytes but a
// worse load/unpack chain; attn is not mask-BW-bound) -> reverted. This round
// is the clean composition A/B that r11 confounded: r9 qkv + r10 gemm_o +
// proven int4 attn, nothing else changed.

#define AS1 __attribute__((address_space(1)))
#define AS3 __attribute__((address_space(3)))

__device__ __forceinline__ void gload_lds16(const bf16* g, bf16* l) {
    __builtin_amdgcn_global_load_lds((const AS1 unsigned int*)g,
                                     (AS3 unsigned int*)l, 16, 0, 0);
}

union Pack8 { bf16 h[8]; uint4 u; };
union Pack4 { bf16 h[4]; unsigned long long u; };

__device__ __forceinline__ void store_pack8(bf16* dst, float4 a, float4 b) {
    Pack8 p;
    p.h[0] = (bf16)a.x; p.h[1] = (bf16)a.y; p.h[2] = (bf16)a.z; p.h[3] = (bf16)a.w;
    p.h[4] = (bf16)b.x; p.h[5] = (bf16)b.y; p.h[6] = (bf16)b.z; p.h[7] = (bf16)b.w;
    *(uint4*)dst = p.u;
}

// ---------------- weight transpose W[K][N] fp32 -> WT[N][K] bf16 -------------
__global__ __launch_bounds__(256) void wtr_kernel(
    const float* __restrict__ Wq, const float* __restrict__ Wk,
    const float* __restrict__ Wv, const float* __restrict__ Wo,
    bf16* __restrict__ WT)
{
    __shared__ float Ts[64][65];
    const int tid = threadIdx.x;
    const int k0 = blockIdx.x * 64;
    const int n0 = blockIdx.y * 64;
    const int z  = blockIdx.z;
    const float* W = (z == 0) ? Wq : (z == 1) ? Wk : (z == 2) ? Wv : Wo;
    bf16* O = WT + (size_t)z * 512 * 512;
    #pragma unroll
    for (int i = 0; i < 16; i++) {
        const int r = i * 4 + (tid >> 6), c = tid & 63;
        Ts[r][c] = W[(size_t)(k0 + r) * 512 + n0 + c];
    }
    __syncthreads();
    #pragma unroll
    for (int i = 0; i < 16; i++) {
        const int a = i * 4 + (tid >> 6), c = tid & 63;
        O[(size_t)(n0 + a) * 512 + k0 + c] = (bf16)Ts[c][a];
    }
}

// ---------------- merged Q/K/V projection GEMM: 128x256 tile (r9 exact) ------
// Grid (64,2,3), 512 thr = 8 waves (2x4), wave = 64x64 (acc[4][4] in AGPR).
// A fp32 reg-staged+cvt (read 2x total); B bf16 via global_load_lds.
// Single-buffer, 2x __syncthreads per iter. Measured 45us.
__global__ __launch_bounds__(512, 3) void gemm_qkv(
    const float* __restrict__ Aq, const float* __restrict__ Ak,
    const float* __restrict__ Av, const bf16* __restrict__ WT,
    const float* __restrict__ Bq, const float* __restrict__ Bk,
    const float* __restrict__ Bv,
    bf16* __restrict__ Oq, bf16* __restrict__ Ok, bf16* __restrict__ Ov)
{
    __shared__ __align__(16) bf16 smem[17408];   // 34816 B (Tsm overlay size)
    bf16* Asm = smem;            // 128x32 = 4096 elems (8 KB)
    bf16* Bsm = smem + 4096;     // 256x32 = 8192 elems (16 KB)

    const int z = blockIdx.z;
    const float* A    = (z == 0) ? Aq : (z == 1) ? Ak : Av;
    const float* bias = (z == 0) ? Bq : (z == 1) ? Bk : Bv;
    bf16* out         = (z == 0) ? Oq : (z == 1) ? Ok : Ov;
    const bf16* BT = WT + (size_t)z * 262144;
    const float scale = (z == 0) ? 0.125f : 1.0f;

    const int tid  = threadIdx.x;
    const int lane = tid & 63;
    const int wave = tid >> 6;
    const int quad = lane >> 4;
    const int l16  = lane & 15;
    const int mblk = blockIdx.x * 128;
    const int nblk = blockIdx.y * 256;

    const int srowA = tid >> 2;
    const int scolA = (tid & 3) * 8;
    const float* Ag = A + (size_t)(mblk + srowA) * 512 + scolA;
    const int aoff = srowA * 32 + scolA;
    const int srowB = wave * 16 + (lane >> 2);
    const int scolB = (lane & 3) * 8;
    const bf16* Bg0 = BT + (size_t)(nblk + srowB) * 512 + scolB;
    const bf16* Bg1 = Bg0 + (size_t)128 * 512;
    bf16* Bl0 = Bsm + wave * 16 * 32;
    bf16* Bl1 = Bsm + (128 + wave * 16) * 32;

    const int wr = (wave >> 2) * 64;     // 2 wave-rows
    const int wc = (wave & 3) * 64;      // 4 wave-cols

    floatx4 acc[4][4] = {};
    for (int k0 = 0; k0 < 512; k0 += 32) {
        gload_lds16(Bg0 + k0, Bl0);
        gload_lds16(Bg1 + k0, Bl1);
        float4 x0 = *(const float4*)(Ag + k0);
        float4 x1 = *(const float4*)(Ag + k0 + 4);
        store_pack8(Asm + aoff, x0, x1);
        __syncthreads();
        bf16x8 a[4], b[4];
        #pragma unroll
        for (int mt = 0; mt < 4; mt++)
            a[mt] = *(const bf16x8*)(Asm + (wr + mt * 16 + l16) * 32 + quad * 8);
        #pragma unroll
        for (int nt = 0; nt < 4; nt++)
            b[nt] = *(const bf16x8*)(Bsm + (wc + nt * 16 + l16) * 32 + quad * 8);
        #pragma unroll
        for (int mt = 0; mt < 4; mt++)
            #pragma unroll
            for (int nt = 0; nt < 4; nt++)
                acc[mt][nt] = __builtin_amdgcn_mfma_f32_16x16x32_bf16(
                    a[mt], b[nt], acc[mt][nt], 0, 0, 0);
        __syncthreads();
    }

    if (z != 2) {
        #pragma unroll
        for (int mt = 0; mt < 4; mt++) {
            #pragma unroll
            for (int nt = 0; nt < 4; nt++) {
                const int colg = nblk + wc + nt * 16 + l16;
                const float bb = bias[colg];
                #pragma unroll
                for (int r = 0; r < 4; r++) {
                    const int rowg = mblk + wr + mt * 16 + quad * 4 + r;
                    const float v = (acc[mt][nt][r] + bb) * scale;
                    const int b_ = rowg >> 12;
                    const int t_ = (rowg >> 3) & 511;
                    const int c  = rowg & 7;
                    const int h  = colg >> 6;
                    const int d  = colg & 63;
                    const int hd = b_ * 64 + h * 8 + c;
                    out[((size_t)hd * 512 + t_) * 64 + d] = (bf16)v;
                }
            }
        }
    } else {
        // V^T transpose epilogue: 2 col-chunks of 128 through Tsm[128][136].
        typedef bf16 TsmRow[136];
        TsmRow* Tsm = (TsmRow*)smem;
        const int b_ = mblk >> 12;
        const int t0 = (mblk >> 3) & 511;
        #pragma unroll
        for (int cb = 0; cb < 2; cb++) {
            if (((wave & 3) >> 1) == cb) {   // waves owning cols [cb*128,+128)
                #pragma unroll
                for (int mt = 0; mt < 4; mt++) {
                    #pragma unroll
                    for (int nt = 0; nt < 4; nt++) {
                        const int clg = wc + nt * 16 + l16;   // local col
                        const float bb = bias[nblk + clg];
                        const int cl = clg - cb * 128;
                        #pragma unroll
                        for (int r = 0; r < 4; r++)
                            Tsm[wr + mt * 16 + quad * 4 + r][cl] =
                                (bf16)(acc[mt][nt][r] + bb);
                    }
                }
            }
            __syncthreads();
            #pragma unroll
            for (int e = tid; e < 1024; e += 512) {
                const int col = e >> 3, c = e & 7;
                const int gcol = nblk + cb * 128 + col;
                const int h = gcol >> 6, d = gcol & 63;
                const int hd = b_ * 64 + h * 8 + c;
                Pack8 lo, hi;
                #pragma unroll
                for (int j = 0; j < 8; j++) lo.h[j] = Tsm[j * 8 + c][col];
                #pragma unroll
                for (int j = 0; j < 8; j++) hi.h[j] = Tsm[(j + 8) * 8 + c][col];
                bf16* dst = out + ((size_t)hd * 64 + d) * 512 + t0;
                *(uint4*)dst = lo.u;
                *(uint4*)(dst + 8) = hi.u;
            }
            __syncthreads();
        }
    }
}

// ---------------- output projection GEMM: 64x128, 4 waves (r10 exact) --------
__global__ __launch_bounds__(256) void gemm_o(
    const bf16* __restrict__ A, const bf16* __restrict__ BT,
    const float* __restrict__ bias, float* __restrict__ out)
{
    __shared__ bf16 Asm[64 * 32];
    __shared__ bf16 Bsm[128 * 32];
    const int tid  = threadIdx.x;
    const int lane = tid & 63;
    const int wave = tid >> 6;
    const int quad = lane >> 4;
    const int l16  = lane & 15;
    const int mblk = blockIdx.x * 64;
    const int nblk = blockIdx.y * 128;

    const int srow = wave * 16 + (lane >> 2);
    const int scol = (lane & 3) * 8;
    const bf16* Ag  = A + (size_t)(mblk + srow) * 512 + scol;
    const bf16* Bg0 = BT + (size_t)(nblk + srow) * 512 + scol;
    const bf16* Bg1 = Bg0 + (size_t)64 * 512;
    bf16* Al  = Asm + wave * 16 * 32;
    bf16* Bl0 = Bsm + wave * 16 * 32;
    bf16* Bl1 = Bsm + (64 + wave * 16) * 32;

    const int wr = (wave >> 1) * 32;
    const int wc = (wave & 1) * 64;

    floatx4 acc[2][4] = {};
    for (int k0 = 0; k0 < 512; k0 += 32) {
        gload_lds16(Ag + k0,  Al);
        gload_lds16(Bg0 + k0, Bl0);
        gload_lds16(Bg1 + k0, Bl1);
        __syncthreads();
        bf16x8 a[2], b[4];
        #pragma unroll
        for (int mt = 0; mt < 2; mt++)
            a[mt] = *(const bf16x8*)(Asm + (wr + mt * 16 + l16) * 32 + quad * 8);
        #pragma unroll
        for (int nt = 0; nt < 4; nt++)
            b[nt] = *(const bf16x8*)(Bsm + (wc + nt * 16 + l16) * 32 + quad * 8);
        #pragma unroll
        for (int mt = 0; mt < 2; mt++)
            #pragma unroll
            for (int nt = 0; nt < 4; nt++)
                acc[mt][nt] = __builtin_amdgcn_mfma_f32_16x16x32_bf16(
                    a[mt], b[nt], acc[mt][nt], 0, 0, 0);
        __syncthreads();
    }

    #pragma unroll
    for (int mt = 0; mt < 2; mt++) {
        #pragma unroll
        for (int nt = 0; nt < 4; nt++) {
            const int colg = nblk + wc + nt * 16 + l16;
            const float bb = bias[colg];
            #pragma unroll
            for (int r = 0; r < 4; r++) {
                const int rowg = mblk + wr + mt * 16 + quad * 4 + r;
                out[(size_t)rowg * 512 + colg] = acc[mt][nt][r] + bb;
            }
        }
    }
}

// ---------------- attention: QBLK=64, swapped QK^T, int4 mask (proven) -------
#define PST 520

__global__ __launch_bounds__(256, 2) void attn_kernel(
    const bf16* __restrict__ Qws, const bf16* __restrict__ Kws,
    const bf16* __restrict__ Vtws, const int* __restrict__ mask,
    bf16* __restrict__ Xws)
{
    __shared__ bf16 Psm[64][PST];
    __shared__ float redM[4][64];
    __shared__ float redS[4][64];
    const int tid  = threadIdx.x;
    const int wave = tid >> 6;
    const int lane = tid & 63;
    const int quad = lane >> 4;
    const int l16  = lane & 15;
    const int s_ = blockIdx.x;
    const int o_ = ((s_ & 7) << 7) | (s_ >> 3);
    const int hd = o_ >> 3;
    const int qt = o_ & 7;
    const int q0 = qt * 64;
    const int b = hd >> 6;
    const int h = (hd >> 3) & 7;
    const int c = hd & 7;

    const bf16* Qh = Qws + (size_t)hd * 512 * 64;
    const bf16* Kh = Kws + (size_t)hd * 512 * 64;
    const int* mp = mask + ((size_t)b * 512 + q0) * 512;

    bf16x8 aq[4][2];
    #pragma unroll
    for (int s = 0; s < 4; s++) {
        aq[s][0] = *(const bf16x8*)(Qh + (size_t)(q0 + s * 16 + l16) * 64 + quad * 8);
        aq[s][1] = *(const bf16x8*)(Qh + (size_t)(q0 + s * 16 + l16) * 64 + 32 + quad * 8);
    }

    floatx4 sv[4][8];
    #pragma unroll
    for (int s = 0; s < 4; s++)
        #pragma unroll
        for (int nt = 0; nt < 8; nt++)
            sv[s][nt] = (floatx4){0.f, 0.f, 0.f, 0.f};

    #pragma unroll
    for (int nt = 0; nt < 8; nt++) {
        const int s0 = wave * 128 + nt * 16;
        bf16x8 bk0 = *(const bf16x8*)(Kh + (size_t)(s0 + l16) * 64 + quad * 8);
        bf16x8 bk1 = *(const bf16x8*)(Kh + (size_t)(s0 + l16) * 64 + 32 + quad * 8);
        #pragma unroll
        for (int s = 0; s < 4; s++) {
            sv[s][nt] = __builtin_amdgcn_mfma_f32_16x16x32_bf16(
                bk0, aq[s][0], sv[s][nt], 0, 0, 0);
            sv[s][nt] = __builtin_amdgcn_mfma_f32_16x16x32_bf16(
                bk1, aq[s][1], sv[s][nt], 0, 0, 0);
        }
    }

    float mx[4] = {-3.0e38f, -3.0e38f, -3.0e38f, -3.0e38f};
    #pragma unroll
    for (int s = 0; s < 4; s++)
        #pragma unroll
        for (int nt = 0; nt < 8; nt++) {
            const int4 mv = *(const int4*)(
                mp + (size_t)(s * 16 + l16) * 512 + wave * 128 + nt * 16 + quad * 4);
            float v0 = sv[s][nt][0] + ((mv.x == 0) ? -1.0e9f : 0.0f);
            float v1 = sv[s][nt][1] + ((mv.y == 0) ? -1.0e9f : 0.0f);
            float v2 = sv[s][nt][2] + ((mv.z == 0) ? -1.0e9f : 0.0f);
            float v3 = sv[s][nt][3] + ((mv.w == 0) ? -1.0e9f : 0.0f);
            sv[s][nt][0] = v0; sv[s][nt][1] = v1;
            sv[s][nt][2] = v2; sv[s][nt][3] = v3;
            mx[s] = fmaxf(mx[s], fmaxf(fmaxf(v0, v1), fmaxf(v2, v3)));
        }
    #pragma unroll
    for (int s = 0; s < 4; s++) {
        mx[s] = fmaxf(mx[s], __shfl_xor(mx[s], 16, 64));
        mx[s] = fmaxf(mx[s], __shfl_xor(mx[s], 32, 64));
    }
    if (quad == 0)
        #pragma unroll
        for (int s = 0; s < 4; s++) redM[wave][s * 16 + l16] = mx[s];
    __syncthreads();

    float mf[4], sum[4] = {0.f, 0.f, 0.f, 0.f};
    #pragma unroll
    for (int s = 0; s < 4; s++) {
        const int qr = s * 16 + l16;
        mf[s] = fmaxf(fmaxf(redM[0][qr], redM[1][qr]),
                      fmaxf(redM[2][qr], redM[3][qr]));
    }
    #pragma unroll
    for (int s = 0; s < 4; s++)
        #pragma unroll
        for (int nt = 0; nt < 8; nt++)
            #pragma unroll
            for (int r = 0; r < 4; r++) {
                const float e = __expf(sv[s][nt][r] - mf[s]);
                sv[s][nt][r] = e;
                sum[s] += e;
            }
    #pragma unroll
    for (int s = 0; s < 4; s++) {
        sum[s] += __shfl_xor(sum[s], 16, 64);
        sum[s] += __shfl_xor(sum[s], 32, 64);
    }
    if (quad == 0)
        #pragma unroll
        for (int s = 0; s < 4; s++) redS[wave][s * 16 + l16] = sum[s];
    __syncthreads();

    float inv[4];
    #pragma unroll
    for (int s = 0; s < 4; s++) {
        const int qr = s * 16 + l16;
        inv[s] = 1.f / (redS[0][qr] + redS[1][qr] + redS[2][qr] + redS[3][qr]);
    }
    #pragma unroll
    for (int s = 0; s < 4; s++)
        #pragma unroll
        for (int nt = 0; nt < 8; nt++) {
            Pack4 pk;
            #pragma unroll
            for (int r = 0; r < 4; r++)
                pk.h[r] = (bf16)(sv[s][nt][r] * inv[s]);
            *(unsigned long long*)&Psm[s * 16 + l16][wave * 128 + nt * 16 + quad * 4]
                = pk.u;
        }
    __syncthreads();

    const bf16* Vh = Vtws + (size_t)hd * 64 * 512;
    const int d0 = wave * 16;
    floatx4 o[4] = {};
    #pragma unroll
    for (int ks = 0; ks < 16; ks++) {
        bf16x8 bv = *(const bf16x8*)(Vh + (size_t)(d0 + l16) * 512 + ks * 32 + quad * 8);
        #pragma unroll
        for (int rt = 0; rt < 4; rt++) {
            bf16x8 ap = *(const bf16x8*)(&Psm[rt * 16 + l16][ks * 32 + quad * 8]);
            o[rt] = __builtin_amdgcn_mfma_f32_16x16x32_bf16(ap, bv, o[rt], 0, 0, 0);
        }
    }
    #pragma unroll
    for (int rt = 0; rt < 4; rt++)
        #pragma unroll
        for (int r = 0; r < 4; r++) {
            const int q = q0 + rt * 16 + quad * 4 + r;
            const size_t row = ((size_t)b * 512 + q) * 8 + c;
            Xws[row * 512 + h * 64 + d0 + l16] = (bf16)o[rt][r];
        }
}

extern "C" void kernel_launch(void* const* d_in, const int* in_sizes, int n_in,
                              void* d_out, int out_size, void* d_ws, size_t ws_size,
                              hipStream_t stream)
{
    const float* qin  = (const float*)d_in[0];
    const float* kin  = (const float*)d_in[1];
    const float* vin  = (const float*)d_in[2];
    const int*   mask = (const int*)d_in[3];
    const float* Bq = (const float*)d_in[5];
    const float* Bk = (const float*)d_in[7];
    const float* Bv = (const float*)d_in[9];
    const float* Bo = (const float*)d_in[11];
    float* out = (float*)d_out;

    const size_t R = (size_t)8192 * 512;
    bf16* r0 = (bf16*)d_ws;
    bf16* r1 = r0 + R;
    bf16* r2 = r1 + R;
    bf16* r3 = r2 + R;
    bf16* WT = r3 + R;

    wtr_kernel<<<dim3(8, 8, 4), dim3(256), 0, stream>>>(
        (const float*)d_in[4], (const float*)d_in[6],
        (const float*)d_in[8], (const float*)d_in[10], WT);
    gemm_qkv<<<dim3(64, 2, 3), dim3(512), 0, stream>>>(
        qin, kin, vin, WT, Bq, Bk, Bv, r0, r1, r2);
    attn_kernel<<<dim3(1024), dim3(256), 0, stream>>>(
        r0, r1, r2, mask, r3);
    gemm_o<<<dim3(128, 4), dim3(256), 0, stream>>>(
        r3, WT + (size_t)3 * 262144, Bo, out);
}